// Round 14
// baseline (218.430 us; speedup 1.0000x reference)
//
#include <hip/hip_runtime.h>
#include <hip/hip_bf16.h>
#include <math.h>
#include <stdint.h>

#define BDIM 8192
#define DDIM 512
#define NT   64        // BDIM / 128
#define BK   64        // K-step staged in LDS
#define TEMP 10.0f

typedef __attribute__((ext_vector_type(8))) short bf16x8;
typedef __attribute__((ext_vector_type(4))) float f32x4;
typedef unsigned long long u64;
typedef unsigned int u32;

__device__ __forceinline__ unsigned short f2bf(float f) {
  unsigned int x = __float_as_uint(f);
  x += 0x7fffu + ((x >> 16) & 1u);   // round-to-nearest-even
  return (unsigned short)(x >> 16);
}

// async global->LDS, 16B per lane; LDS dest = wave-uniform base + lane*16
__device__ __forceinline__ void gld16(const void* gptr, void* lptr) {
  __builtin_amdgcn_global_load_lds((const __attribute__((address_space(1))) u32*)gptr,
                                   (__attribute__((address_space(3))) u32*)lptr, 16, 0, 0);
}

// Butterfly sum over 16-lane groups via DPP (xor 1,2,7,15 spans 4-bit space).
__device__ __forceinline__ float red16_dpp(float x) {
  x += __int_as_float(__builtin_amdgcn_mov_dpp(__float_as_int(x), 0xB1, 0xF, 0xF, true));
  x += __int_as_float(__builtin_amdgcn_mov_dpp(__float_as_int(x), 0x4E, 0xF, 0xF, true));
  x += __int_as_float(__builtin_amdgcn_mov_dpp(__float_as_int(x), 0x141, 0xF, 0xF, true));
  x += __int_as_float(__builtin_amdgcn_mov_dpp(__float_as_int(x), 0x140, 0xF, 0xF, true));
  return x;
}

// ---------------- kernel 1: normalize rows, fold TEMP3 into u, store bf16 ----
__global__ __launch_bounds__(256) void knorm(const float* __restrict__ cnn,
                                             const float* __restrict__ rnn,
                                             unsigned short* __restrict__ u,
                                             unsigned short* __restrict__ v) {
  int wid = threadIdx.x >> 6, lane = threadIdx.x & 63;
  int gw = blockIdx.x * 4 + wid;          // 0 .. 2*BDIM-1
  const float* src;
  unsigned short* dst;
  int row;
  float mul;
  if (gw < BDIM) { src = cnn; dst = u; row = gw; mul = TEMP; }
  else           { src = rnn; dst = v; row = gw - BDIM; mul = 1.0f; }
  const float* p = src + (size_t)row * DDIM + lane * 8;
  float4 a0 = *(const float4*)p;
  float4 a1 = *(const float4*)(p + 4);
  float ss = a0.x*a0.x + a0.y*a0.y + a0.z*a0.z + a0.w*a0.w
           + a1.x*a1.x + a1.y*a1.y + a1.z*a1.z + a1.w*a1.w;
#pragma unroll
  for (int m = 1; m <= 32; m <<= 1) ss += __shfl_xor(ss, m);
  float inv = mul / sqrtf(ss);
  unsigned short o[8];
  o[0] = f2bf(a0.x * inv); o[1] = f2bf(a0.y * inv);
  o[2] = f2bf(a0.z * inv); o[3] = f2bf(a0.w * inv);
  o[4] = f2bf(a1.x * inv); o[5] = f2bf(a1.y * inv);
  o[6] = f2bf(a1.z * inv); o[7] = f2bf(a1.w * inv);
  *(uint4*)(dst + (size_t)row * DDIM + lane * 8) = *(uint4*)o;
}

// ---------------- kernel 2: fused GEMM + pipelined mask build + reductions ---
// R13 structure with ONE change: mask loads are issued one iteration EARLY
// (inside the compute phase, drained by barrier2 under the MFMA shadow) and
// balloted at the top of the next compute phase. The barrier before MFMA no
// longer exposes the mask loads' HBM latency.
__global__ __launch_bounds__(256, 3) void kmain(const unsigned short* __restrict__ u,
                                                const unsigned short* __restrict__ v,
                                                const float* __restrict__ idx,
                                                const float* __restrict__ probs,
                                                float* __restrict__ P) {
  __shared__ unsigned short aT[128 * BK];   // [row][chunk^row&7] swizzled, 16 KB
  __shared__ unsigned short bT[128 * BK];   // 16 KB
  __shared__ float L0[5 * 128];
  __shared__ float L1[3 * 128];
  __shared__ u64 m0p[128][2], m0n[128][2];  // loss0: rows I+r, word h = cols J+h*64..
  __shared__ u64 m1p[128][2], m1n[128][2];  // loss1: rows J+r, word h = cols I+h*64..
  const int tid = threadIdx.x, lane = tid & 63, wid = tid >> 6;
  const int l15 = lane & 15, lg = lane >> 4;
  const int qr = wid >> 1, qc = wid & 1;

  for (int t = tid; t < 1024; t += 256) {
    if (t < 640) L0[t] = 0.f; else L1[t - 640] = 0.f;
  }

  // supertile remap (bijective over 64x64 tiles): XCD k owns ti-band k*8..k*8+7
  const int bid = blockIdx.x;
  const int xcd = bid & 7, n = bid >> 3;
  const int st = n >> 6, w = n & 63;
  const int ti = xcd * 8 + (w & 7);
  const int tj = st * 8 + (w >> 3);
  const int I = ti * 128, J = tj * 128;

  const float th1 = probs[0], th2 = probs[1];

  f32x4 acc[4][4];
#pragma unroll
  for (int a = 0; a < 4; a++)
#pragma unroll
    for (int b = 0; b < 4; b++) acc[a][b] = (f32x4){0, 0, 0, 0};

  // staging: wave wid stages rows wid*32 .. wid*32+31 of A and B.
  // chunk c = 8 rows (1024 B LDS); lane l -> row +(l>>3); SOURCE k-chunk is
  // pre-swizzled (l&7)^((l>>3)&7) so the linear LDS write lands swizzled.
  const int srcsw = ((lane & 7) ^ ((lane >> 3) & 7)) * 8;
  const unsigned short* gA = u + (size_t)(I + wid * 32 + (lane >> 3)) * DDIM + srcsw;
  const unsigned short* gB = v + (size_t)(J + wid * 32 + (lane >> 3)) * DDIM + srcsw;
  unsigned short* lA = aT + (wid * 32 + (lane >> 3)) * BK + (lane & 7) * 8;
  unsigned short* lB = bT + (wid * 32 + (lane >> 3)) * BK + (lane & 7) * 8;
  const int rsw = (l15 & 7);                // read-side row XOR

  // mask-load helper state: iteration t covers rows wid*32 + t*4 .. +3
  float mx0[4][2], mx1[4][2];
#define LOADMASK(t_)                                                          \
  {                                                                           \
    const int rb_ = wid * 32 + (t_) * 4;                                      \
    _Pragma("unroll")                                                         \
    for (int rr = 0; rr < 4; rr++)                                            \
      _Pragma("unroll")                                                       \
      for (int h = 0; h < 2; h++) {                                           \
        mx0[rr][h] = idx[(size_t)(I + rb_ + rr) * BDIM + J + h * 64 + lane];  \
        mx1[rr][h] = idx[(size_t)(J + rb_ + rr) * BDIM + I + h * 64 + lane];  \
      }                                                                       \
  }

  LOADMASK(0);                       // prologue issue; drained by first barrier

  for (int t = 0; t < 8; ++t) {
    const int k0 = t * BK;
#pragma unroll
    for (int c = 0; c < 4; c++) {
      gld16(gA + (size_t)c * 8 * DDIM + k0, lA + c * 8 * BK);
      gld16(gB + (size_t)c * 8 * DDIM + k0, lB + c * 8 * BK);
    }
    __syncthreads();   // drains staging(t); mask(t) already drained last iter
    // ballot mask(t) into LDS (data arrived >= one barrier ago)
    {
      const int rbase = wid * 32 + t * 4;
#pragma unroll
      for (int rr = 0; rr < 4; rr++)
#pragma unroll
        for (int h = 0; h < 2; h++) {
          u64 p0 = __ballot(mx0[rr][h] > th1);
          u64 n0 = __ballot(mx0[rr][h] <= th2);
          u64 p1 = __ballot(mx1[rr][h] > th1);
          u64 n1 = __ballot(mx1[rr][h] <= th2);
          if (lane == 0) {
            m0p[rbase + rr][h] = p0; m0n[rbase + rr][h] = n0;
            m1p[rbase + rr][h] = p1; m1n[rbase + rr][h] = n1;
          }
        }
    }
    if (t < 7) LOADMASK(t + 1);      // issue early: barrier2 drains under MFMA
#pragma unroll
    for (int kk = 0; kk < 2; kk++) {
      bf16x8 af[4], bf_[4];
#pragma unroll
      for (int ar = 0; ar < 4; ar++)
        af[ar] = *(const bf16x8*)(aT + (qr * 64 + ar * 16 + l15) * BK + ((kk * 4 + lg) ^ rsw) * 8);
#pragma unroll
      for (int bc = 0; bc < 4; bc++)
        bf_[bc] = *(const bf16x8*)(bT + (qc * 64 + bc * 16 + l15) * BK + ((kk * 4 + lg) ^ rsw) * 8);
#pragma unroll
      for (int ar = 0; ar < 4; ar++)
#pragma unroll
        for (int bc = 0; bc < 4; bc++)
          acc[ar][bc] = __builtin_amdgcn_mfma_f32_16x16x32_bf16(af[ar], bf_[bc], acc[ar][bc], 0, 0, 0);
    }
    __syncthreads();   // all reads done; drains mask(t+1) under MFMA shadow
  }
#undef LOADMASK

  // ---- preload loss1 mask words (per-lane row J+C, from LDS) ----
  u64 pw1[4], nw1[4];
#pragma unroll
  for (int bc = 0; bc < 4; bc++) {
    int C = qc * 64 + bc * 16 + l15;
    pw1[bc] = m1p[C][qr] >> (lg * 4);
    nw1[bc] = m1n[C][qr] >> (lg * 4);
  }

  float zn1[4] = {0, 0, 0, 0}, zp1[4] = {0, 0, 0, 0}, sm1[4] = {0, 0, 0, 0};

  // ---- merged pass: loss0 row stats (+row counts) + loss1 column accum ----
#pragma unroll
  for (int ar = 0; ar < 4; ar++) {
    u64 pw[4], nw[4];
#pragma unroll
    for (int j = 0; j < 4; j++) {
      int R = qr * 64 + ar * 16 + lg * 4 + j;
      pw[j] = m0p[R][qc] >> l15;          // broadcast within 16-lane group
      nw[j] = m0n[R][qc] >> l15;
    }
#pragma unroll
    for (int j = 0; j < 4; j++) {
      float zn0 = 0, zp0 = 0, sm0 = 0, cp0 = 0, cn0 = 0;
#pragma unroll
      for (int bc = 0; bc < 4; bc++) {
        float s = acc[ar][bc][j];
        float e = __expf(s - TEMP);
        float mp0 = (float)((unsigned)(pw[j]  >> (bc * 16)) & 1u);
        float mn0 = (float)((unsigned)(nw[j]  >> (bc * 16)) & 1u);
        float mp1 = (float)((unsigned)(pw1[bc] >> (ar * 16 + j)) & 1u);
        float mn1 = (float)((unsigned)(nw1[bc] >> (ar * 16 + j)) & 1u);
        zp0 = fmaf(mp0, e, zp0);
        sm0 = fmaf(mp0, s, sm0);
        zn0 = fmaf(mn0, e, zn0);
        cp0 += mp0;
        cn0 += mn0;
        zp1[bc] = fmaf(mp1, e, zp1[bc]);
        sm1[bc] = fmaf(mp1, s, sm1[bc]);
        zn1[bc] = fmaf(mn1, e, zn1[bc]);
      }
      zn0 = red16_dpp(zn0); zp0 = red16_dpp(zp0); sm0 = red16_dpp(sm0);
      cp0 = red16_dpp(cp0); cn0 = red16_dpp(cn0);
      if (l15 == 0) {
        int R = qr * 64 + ar * 16 + lg * 4 + j;
        atomicAdd(&L0[0 * 128 + R], zn0);
        atomicAdd(&L0[1 * 128 + R], zp0);
        atomicAdd(&L0[2 * 128 + R], sm0);
        atomicAdd(&L0[3 * 128 + R], cp0);
        atomicAdd(&L0[4 * 128 + R], cn0);
      }
    }
  }

  // ---- loss1: reduce over lg groups, then LDS ----
#pragma unroll
  for (int bc = 0; bc < 4; bc++) {
    float zn = zn1[bc], zp = zp1[bc], sm = sm1[bc];
    zn += __shfl_xor(zn, 16); zn += __shfl_xor(zn, 32);
    zp += __shfl_xor(zp, 16); zp += __shfl_xor(zp, 32);
    sm += __shfl_xor(sm, 16); sm += __shfl_xor(sm, 32);
    if (lg == 0) {
      int C = qc * 64 + bc * 16 + l15;
      atomicAdd(&L1[0 * 128 + C], zn);
      atomicAdd(&L1[1 * 128 + C], zp);
      atomicAdd(&L1[2 * 128 + C], sm);
    }
  }
  __syncthreads();

  // ---- write private slots (plain coalesced stores) ----
  for (int t = tid; t < 1024; t += 256) {
    int s = t >> 7, c = t & 127;
    if (s < 5) P[((size_t)tj * 8 + s) * BDIM + I + c] = L0[s * 128 + c];
    else       P[((size_t)ti * 8 + s) * BDIM + J + c] = L1[(s - 5) * 128 + c];
  }
}

// ---------------- kernel 3: reduce slots, per-row loss, block partials --------
__global__ __launch_bounds__(128) void kfinal(const float* __restrict__ P,
                                              float* __restrict__ part) {
  int r = blockIdx.x * 128 + threadIdx.x;
  float st[8] = {0, 0, 0, 0, 0, 0, 0, 0};
  for (int k = 0; k < 64; k++) {
#pragma unroll
    for (int s = 0; s < 8; s++) st[s] += P[((size_t)k * 8 + s) * BDIM + r];
  }
  float np = st[3], nn = st[4];
  float inv = 1.f / (np * (1.f + nn));
  // sum_{pos} log(1+e^{lse-s}) = np*lse - sum_pos(s) + Zp/Zn  (2nd order ~1e-11)
  float l0 = (np * (TEMP + logf(st[0])) - st[2] + st[1] / st[0]) * inv;
  float l1 = (np * (TEMP + logf(st[5])) - st[7] + st[6] / st[5]) * inv;
  float tot = l0 + l1;
#pragma unroll
  for (int m = 1; m <= 32; m <<= 1) tot += __shfl_xor(tot, m);
  __shared__ float sb;
  if (threadIdx.x == 0) sb = tot;
  __syncthreads();
  if (threadIdx.x == 64) part[blockIdx.x] = sb + tot;
}

__global__ __launch_bounds__(64) void kfinal2(const float* __restrict__ part,
                                              float* __restrict__ out) {
  float t = part[threadIdx.x];
#pragma unroll
  for (int m = 1; m <= 32; m <<= 1) t += __shfl_xor(t, m);
  if (threadIdx.x == 0) out[0] = t / (float)BDIM;
}

extern "C" void kernel_launch(void* const* d_in, const int* in_sizes, int n_in,
                              void* d_out, int out_size, void* d_ws, size_t ws_size,
                              hipStream_t stream) {
  (void)in_sizes; (void)n_in; (void)out_size; (void)ws_size;
  const float* cnn   = (const float*)d_in[0];
  const float* rnn   = (const float*)d_in[1];
  const float* idx   = (const float*)d_in[2];
  const float* probs = (const float*)d_in[3];
  char* w = (char*)d_ws;
  unsigned short* u  = (unsigned short*)w;                                   // 8 MB
  unsigned short* v  = (unsigned short*)(w + 8388608);                       // 8 MB
  float* P    = (float*)(w + 16777216);                                      // 16.78 MB
  float* part = (float*)(w + 33554432);                                      // 256 B

  knorm<<<(2 * BDIM) / 4, 256, 0, stream>>>(cnn, rnn, u, v);
  kmain<<<NT * NT, 256, 0, stream>>>(u, v, idx, probs, P);
  kfinal<<<BDIM / 128, 128, 0, stream>>>(P, part);
  kfinal2<<<1, 64, 0, stream>>>(part, (float*)d_out);
}

// Round 15
// 209.184 us; speedup vs baseline: 1.0442x; 1.0442x over previous
//
#include <hip/hip_runtime.h>
#include <hip/hip_bf16.h>
#include <math.h>
#include <stdint.h>

#define BDIM 8192
#define DDIM 512
#define NT   64        // BDIM / 128
#define BK   64        // K-step staged in LDS
#define TEMP 10.0f
#define PLW  128       // plane row stride in u64 words (8192 bits)

typedef __attribute__((ext_vector_type(8))) short bf16x8;
typedef __attribute__((ext_vector_type(4))) float f32x4;
typedef unsigned long long u64;
typedef unsigned int u32;

__device__ __forceinline__ unsigned short f2bf(float f) {
  unsigned int x = __float_as_uint(f);
  x += 0x7fffu + ((x >> 16) & 1u);   // round-to-nearest-even
  return (unsigned short)(x >> 16);
}

// async global->LDS, 16B per lane; LDS dest = wave-uniform base + lane*16
__device__ __forceinline__ void gld16(const void* gptr, void* lptr) {
  __builtin_amdgcn_global_load_lds((const __attribute__((address_space(1))) u32*)gptr,
                                   (__attribute__((address_space(3))) u32*)lptr, 16, 0, 0);
}

// Butterfly sum over 16-lane groups via DPP (xor 1,2,7,15 spans 4-bit space).
__device__ __forceinline__ float red16_dpp(float x) {
  x += __int_as_float(__builtin_amdgcn_mov_dpp(__float_as_int(x), 0xB1, 0xF, 0xF, true));
  x += __int_as_float(__builtin_amdgcn_mov_dpp(__float_as_int(x), 0x4E, 0xF, 0xF, true));
  x += __int_as_float(__builtin_amdgcn_mov_dpp(__float_as_int(x), 0x141, 0xF, 0xF, true));
  x += __int_as_float(__builtin_amdgcn_mov_dpp(__float_as_int(x), 0x140, 0xF, 0xF, true));
  return x;
}

// ---------------- kernel 1: normalize rows, fold TEMP3 into u, store bf16 ----
__global__ __launch_bounds__(256) void knorm(const float* __restrict__ cnn,
                                             const float* __restrict__ rnn,
                                             unsigned short* __restrict__ u,
                                             unsigned short* __restrict__ v) {
  int wid = threadIdx.x >> 6, lane = threadIdx.x & 63;
  int gw = blockIdx.x * 4 + wid;          // 0 .. 2*BDIM-1
  const float* src;
  unsigned short* dst;
  int row;
  float mul;
  if (gw < BDIM) { src = cnn; dst = u; row = gw; mul = TEMP; }
  else           { src = rnn; dst = v; row = gw - BDIM; mul = 1.0f; }
  const float* p = src + (size_t)row * DDIM + lane * 8;
  float4 a0 = *(const float4*)p;
  float4 a1 = *(const float4*)(p + 4);
  float ss = a0.x*a0.x + a0.y*a0.y + a0.z*a0.z + a0.w*a0.w
           + a1.x*a1.x + a1.y*a1.y + a1.z*a1.z + a1.w*a1.w;
#pragma unroll
  for (int m = 1; m <= 32; m <<= 1) ss += __shfl_xor(ss, m);
  float inv = mul / sqrtf(ss);
  unsigned short o[8];
  o[0] = f2bf(a0.x * inv); o[1] = f2bf(a0.y * inv);
  o[2] = f2bf(a0.z * inv); o[3] = f2bf(a0.w * inv);
  o[4] = f2bf(a1.x * inv); o[5] = f2bf(a1.y * inv);
  o[6] = f2bf(a1.z * inv); o[7] = f2bf(a1.w * inv);
  *(uint4*)(dst + (size_t)row * DDIM + lane * 8) = *(uint4*)o;
}

// ---------------- kernel 1b: stream idx -> pos/neg bit-planes + row counts ---
// At 6.06 TB/s measured (96% of ceiling) — do not touch.
__global__ __launch_bounds__(256) void kmask(const float* __restrict__ idx,
                                             const float* __restrict__ probs,
                                             unsigned char* __restrict__ posb,
                                             unsigned char* __restrict__ negb,
                                             float* __restrict__ npr,
                                             float* __restrict__ nnr) {
  const float th1 = probs[0], th2 = probs[1];
  int wid = threadIdx.x >> 6, lane = threadIdx.x & 63;
  int row = blockIdx.x * 4 + wid;         // 2048 blocks x 4 waves = 8192 rows
  const float4* src = (const float4*)(idx + (size_t)row * BDIM);
  unsigned char* pr = posb + (size_t)row * 1024;
  unsigned char* nr = negb + (size_t)row * 1024;
  int np = 0, nn = 0;
#pragma unroll 2
  for (int i = 0; i < 16; i++) {          // 16 chunks of 512 cols
    float4 x0 = src[i * 128 + lane * 2];
    float4 x1 = src[i * 128 + lane * 2 + 1];
    float xs[8] = {x0.x, x0.y, x0.z, x0.w, x1.x, x1.y, x1.z, x1.w};
    unsigned pb = 0, nb = 0;
#pragma unroll
    for (int k = 0; k < 8; k++) {
      pb |= (xs[k] > th1 ? 1u : 0u) << k;
      nb |= (xs[k] <= th2 ? 1u : 0u) << k;
    }
    pr[i * 64 + lane] = (unsigned char)pb;
    nr[i * 64 + lane] = (unsigned char)nb;
    np += __popc(pb); nn += __popc(nb);
  }
#pragma unroll
  for (int m = 1; m <= 32; m <<= 1) {
    np += __shfl_xor(np, m);
    nn += __shfl_xor(nn, m);
  }
  if (lane == 0) { npr[row] = (float)np; nnr[row] = (float)nn; }
}

// ---------------- kernel 2: LDS-staged GEMM (XOR-swizzled) + reductions ------
// R11 structure: 128x128 tile, 4 waves (2x2 quadrants of 64x64), BK=64,
// 2-barrier K-loop, chunk-XOR swizzle (rule #21), supertile XCD remap,
// 3 WGs/CU. R15: K-loop fully unrolled; final iteration peeled with its
// trailing barrier elided (nothing rewrites aT/bT after the last MFMA; L0/L1
// atomics are fenced by the post-epilogue barrier).
__global__ __launch_bounds__(256, 3) void kmain(const unsigned short* __restrict__ u,
                                                const unsigned short* __restrict__ v,
                                                const u64* __restrict__ posp,
                                                const u64* __restrict__ negp,
                                                float* __restrict__ P) {
  __shared__ unsigned short aT[128 * BK];   // [row][chunk^row&7] swizzled, 16 KB
  __shared__ unsigned short bT[128 * BK];   // 16 KB
  __shared__ float L0[3 * 128];
  __shared__ float L1[3 * 128];
  const int tid = threadIdx.x, lane = tid & 63, wid = tid >> 6;
  const int l15 = lane & 15, lg = lane >> 4;
  const int qr = wid >> 1, qc = wid & 1;

  for (int t = tid; t < 768; t += 256) {
    if (t < 384) L0[t] = 0.f; else L1[t - 384] = 0.f;
  }

  // supertile remap (bijective over 64x64 tiles): XCD k owns ti-band k*8..k*8+7
  const int bid = blockIdx.x;
  const int xcd = bid & 7, n = bid >> 3;
  const int st = n >> 6, w = n & 63;
  const int ti = xcd * 8 + (w & 7);
  const int tj = st * 8 + (w >> 3);
  const int I = ti * 128, J = tj * 128;

  // ---- preload loss1 mask words early: latency hides under the K-loop ----
  u64 pw1[4], nw1[4];
#pragma unroll
  for (int bc = 0; bc < 4; bc++) {
    size_t w1 = (size_t)(J + qc * 64 + bc * 16 + l15) * PLW + (I >> 6) + qr;
    pw1[bc] = posp[w1] >> (lg * 4);
    nw1[bc] = negp[w1] >> (lg * 4);
  }

  f32x4 acc[4][4];
#pragma unroll
  for (int a = 0; a < 4; a++)
#pragma unroll
    for (int b = 0; b < 4; b++) acc[a][b] = (f32x4){0, 0, 0, 0};

  // staging: wave wid stages rows wid*32 .. wid*32+31 of A and B.
  // chunk c = 8 rows (1024 B LDS); lane l -> row +(l>>3); SOURCE k-chunk is
  // pre-swizzled (l&7)^((l>>3)&7) so the linear LDS write lands swizzled.
  const int srcsw = ((lane & 7) ^ ((lane >> 3) & 7)) * 8;
  const unsigned short* gA = u + (size_t)(I + wid * 32 + (lane >> 3)) * DDIM + srcsw;
  const unsigned short* gB = v + (size_t)(J + wid * 32 + (lane >> 3)) * DDIM + srcsw;
  unsigned short* lA = aT + (wid * 32 + (lane >> 3)) * BK + (lane & 7) * 8;
  unsigned short* lB = bT + (wid * 32 + (lane >> 3)) * BK + (lane & 7) * 8;
  const int rsw = (l15 & 7);                // read-side row XOR

#define STAGE(k0_)                                                            \
  {                                                                           \
    _Pragma("unroll")                                                         \
    for (int c = 0; c < 4; c++) {                                             \
      gld16(gA + (size_t)c * 8 * DDIM + (k0_), lA + c * 8 * BK);              \
      gld16(gB + (size_t)c * 8 * DDIM + (k0_), lB + c * 8 * BK);              \
    }                                                                         \
  }
#define COMPUTE()                                                             \
  {                                                                           \
    _Pragma("unroll")                                                         \
    for (int kk = 0; kk < 2; kk++) {                                          \
      bf16x8 af[4], bf_[4];                                                   \
      _Pragma("unroll")                                                       \
      for (int ar = 0; ar < 4; ar++)                                          \
        af[ar] = *(const bf16x8*)(aT + (qr * 64 + ar * 16 + l15) * BK + ((kk * 4 + lg) ^ rsw) * 8); \
      _Pragma("unroll")                                                       \
      for (int bc = 0; bc < 4; bc++)                                          \
        bf_[bc] = *(const bf16x8*)(bT + (qc * 64 + bc * 16 + l15) * BK + ((kk * 4 + lg) ^ rsw) * 8); \
      _Pragma("unroll")                                                       \
      for (int ar = 0; ar < 4; ar++)                                          \
        _Pragma("unroll")                                                     \
        for (int bc = 0; bc < 4; bc++)                                        \
          acc[ar][bc] = __builtin_amdgcn_mfma_f32_16x16x32_bf16(af[ar], bf_[bc], acc[ar][bc], 0, 0, 0); \
    }                                                                         \
  }

#pragma unroll
  for (int t = 0; t < 7; ++t) {
    STAGE(t * BK);
    __syncthreads();   // compiler drains vmcnt before barrier
    COMPUTE();
    __syncthreads();   // all reads done before next-step overwrite
  }
  STAGE(7 * BK);
  __syncthreads();
  COMPUTE();           // peeled: no trailing barrier needed (no aT/bT reuse)
#undef STAGE
#undef COMPUTE

  float zn1[4] = {0, 0, 0, 0}, zp1[4] = {0, 0, 0, 0}, sm1[4] = {0, 0, 0, 0};

  // ---- merged pass: loss0 row stats + loss1 column accumulation ----
#pragma unroll
  for (int ar = 0; ar < 4; ar++) {
    u64 pw[4], nw[4];
#pragma unroll
    for (int j = 0; j < 4; j++) {
      int R = qr * 64 + ar * 16 + lg * 4 + j;
      size_t w0 = (size_t)(I + R) * PLW + (J >> 6) + qc;
      pw[j] = posp[w0] >> l15;           // broadcast within 16-lane group
      nw[j] = negp[w0] >> l15;
    }
#pragma unroll
    for (int j = 0; j < 4; j++) {
      float zn0 = 0, zp0 = 0, sm0 = 0;
#pragma unroll
      for (int bc = 0; bc < 4; bc++) {
        float s = acc[ar][bc][j];
        float e = __expf(s - TEMP);
        float mp0 = (float)((unsigned)(pw[j]  >> (bc * 16)) & 1u);
        float mn0 = (float)((unsigned)(nw[j]  >> (bc * 16)) & 1u);
        float mp1 = (float)((unsigned)(pw1[bc] >> (ar * 16 + j)) & 1u);
        float mn1 = (float)((unsigned)(nw1[bc] >> (ar * 16 + j)) & 1u);
        zp0 = fmaf(mp0, e, zp0);
        sm0 = fmaf(mp0, s, sm0);
        zn0 = fmaf(mn0, e, zn0);
        zp1[bc] = fmaf(mp1, e, zp1[bc]);
        sm1[bc] = fmaf(mp1, s, sm1[bc]);
        zn1[bc] = fmaf(mn1, e, zn1[bc]);
      }
      zn0 = red16_dpp(zn0); zp0 = red16_dpp(zp0); sm0 = red16_dpp(sm0);
      if (l15 == 0) {
        int R = qr * 64 + ar * 16 + lg * 4 + j;
        atomicAdd(&L0[0 * 128 + R], zn0);
        atomicAdd(&L0[1 * 128 + R], zp0);
        atomicAdd(&L0[2 * 128 + R], sm0);
      }
    }
  }

  // ---- loss1: reduce over lg groups, then LDS ----
#pragma unroll
  for (int bc = 0; bc < 4; bc++) {
    float zn = zn1[bc], zp = zp1[bc], sm = sm1[bc];
    zn += __shfl_xor(zn, 16); zn += __shfl_xor(zn, 32);
    zp += __shfl_xor(zp, 16); zp += __shfl_xor(zp, 32);
    sm += __shfl_xor(sm, 16); sm += __shfl_xor(sm, 32);
    if (lg == 0) {
      int C = qc * 64 + bc * 16 + l15;
      atomicAdd(&L1[0 * 128 + C], zn);
      atomicAdd(&L1[1 * 128 + C], zp);
      atomicAdd(&L1[2 * 128 + C], sm);
    }
  }
  __syncthreads();

  // ---- write private slots (plain coalesced stores) ----
  for (int t = tid; t < 768; t += 256) {
    int s = t >> 7, c = t & 127;
    if (s < 3) P[((size_t)tj * 6 + s) * BDIM + I + c] = L0[s * 128 + c];
    else       P[((size_t)ti * 6 + s) * BDIM + J + c] = L1[(s - 3) * 128 + c];
  }
}

// ---------------- kernel 3: reduce slots, per-row loss, block partials --------
__global__ __launch_bounds__(128) void kfinal(const float* __restrict__ P,
                                              const float* __restrict__ npr,
                                              const float* __restrict__ nnr,
                                              float* __restrict__ part) {
  int r = blockIdx.x * 128 + threadIdx.x;
  float st[6] = {0, 0, 0, 0, 0, 0};
  for (int k = 0; k < 64; k++) {
#pragma unroll
    for (int s = 0; s < 6; s++) st[s] += P[((size_t)k * 6 + s) * BDIM + r];
  }
  float np = npr[r], nn = nnr[r];
  float inv = 1.f / (np * (1.f + nn));
  // sum_{pos} log(1+e^{lse-s}) = np*lse - sum_pos(s) + Zp/Zn  (2nd order ~1e-11)
  float l0 = (np * (TEMP + logf(st[0])) - st[2] + st[1] / st[0]) * inv;
  float l1 = (np * (TEMP + logf(st[3])) - st[5] + st[4] / st[3]) * inv;
  float tot = l0 + l1;
#pragma unroll
  for (int m = 1; m <= 32; m <<= 1) tot += __shfl_xor(tot, m);
  __shared__ float sb;
  if (threadIdx.x == 0) sb = tot;
  __syncthreads();
  if (threadIdx.x == 64) part[blockIdx.x] = sb + tot;
}

__global__ __launch_bounds__(64) void kfinal2(const float* __restrict__ part,
                                              float* __restrict__ out) {
  float t = part[threadIdx.x];
#pragma unroll
  for (int m = 1; m <= 32; m <<= 1) t += __shfl_xor(t, m);
  if (threadIdx.x == 0) out[0] = t / (float)BDIM;
}

extern "C" void kernel_launch(void* const* d_in, const int* in_sizes, int n_in,
                              void* d_out, int out_size, void* d_ws, size_t ws_size,
                              hipStream_t stream) {
  (void)in_sizes; (void)n_in; (void)out_size; (void)ws_size;
  const float* cnn   = (const float*)d_in[0];
  const float* rnn   = (const float*)d_in[1];
  const float* idx   = (const float*)d_in[2];
  const float* probs = (const float*)d_in[3];
  char* w = (char*)d_ws;
  unsigned short* u  = (unsigned short*)w;                                   // 8 MB
  unsigned short* v  = (unsigned short*)(w + 8388608);                       // 8 MB
  unsigned char* posb = (unsigned char*)(w + 16777216);                      // 8 MB
  unsigned char* negb = (unsigned char*)(w + 25165824);                      // 8 MB
  float* P    = (float*)(w + 33554432);                                      // 12.58 MB
  float* npr  = (float*)(w + 46137344);                                      // 32 KB
  float* nnr  = (float*)(w + 46170112);                                      // 32 KB
  float* part = (float*)(w + 46202880);                                      // 256 B

  knorm<<<(2 * BDIM) / 4, 256, 0, stream>>>(cnn, rnn, u, v);
  kmask<<<BDIM / 4, 256, 0, stream>>>(idx, probs, posb, negb, npr, nnr);
  kmain<<<NT * NT, 256, 0, stream>>>(u, v, (const u64*)posb, (const u64*)negb, P);
  kfinal<<<BDIM / 128, 128, 0, stream>>>(P, npr, nnr, part);
  kfinal2<<<1, 64, 0, stream>>>(part, (float*)d_out);
}